// Round 19
// baseline (65.679 us; speedup 1.0000x reference)
//
#include <hip/hip_runtime.h>
#include <hip/hip_bf16.h>
#include <stdint.h>

#define B_   64
#define T_   8192
#define D_   128
#define L_   64
#define SUB  64        // tokens per subchunk
#define NSC  128       // subchunk slots per batch (T/SUB)
#define NXB  32        // blocks per batch; each owns NSC/NXB = 4 subchunk slots
#define XSF  136       // padded LDS row stride (bf16 elems), HW-verified layout

typedef float f32x4 __attribute__((ext_vector_type(4)));
typedef short s16x8 __attribute__((ext_vector_type(8)));
typedef short s16x4 __attribute__((ext_vector_type(4)));

__device__ __forceinline__ uint16_t f2bf(float f) {
  __hip_bfloat16 h = __float2bfloat16(f);          // HW RNE
  return *(uint16_t*)&h;
}
__device__ __forceinline__ float bfbits2f(uint16_t h) {
  union { uint32_t u; float f; } c; c.u = ((uint32_t)h) << 16; return c.f;
}

// DPP row_ror reduces (r10-verified: -21%): VALU-pipe cross-lane, 16-lane rows.
template <int CTRL>
__device__ __forceinline__ float dpp_add(float v) {
  int t = __builtin_amdgcn_update_dpp(0, __builtin_bit_cast(int, v), CTRL, 0xf, 0xf, false);
  return v + __builtin_bit_cast(float, t);
}
template <int CTRL>
__device__ __forceinline__ float dpp_max(float v) {
  int t = __builtin_amdgcn_update_dpp(0, __builtin_bit_cast(int, v), CTRL, 0xf, 0xf, false);
  return fmaxf(v, __builtin_bit_cast(float, t));
}
__device__ __forceinline__ float rdlane(float v, int lane) {
  return __builtin_bit_cast(float, __builtin_amdgcn_readlane(__builtin_bit_cast(int, v), lane));
}

// ---------------------------------------------------------------------------
// prep: blocks 0..15 pack W_k/W_q into bf16 hi/lo MFMA B-fragment order;
// block 16 normalizes lengths (robust to int32 OR int64 input).
// B-frag: n = w*16 + (lane&15); k = kk*32 + 4*(lane>>4) + (j&3) + 16*(j>>2)
// frag id = mat*32 + term*16 + w*4 + kk.   (HW-verified r2-r18)
// ---------------------------------------------------------------------------
__global__ void prep(const float* __restrict__ key_w,
                     const float* __restrict__ query_w,
                     const void* __restrict__ lengths_raw,
                     uint16_t* __restrict__ wfrag,
                     int* __restrict__ lens) {
  if (blockIdx.x == 16) {
    const int tid = threadIdx.x;
    if (tid >= 64) return;
    const int* s32 = (const int*)lengths_raw;
    bool odd_zero = (tid < 32) ? (s32[2 * tid + 1] == 0) : true;
    bool is64 = __all(odd_zero);
    int v;
    if (is64) v = (int)((const long long*)lengths_raw)[tid];
    else      v = s32[tid];
    lens[tid] = v;
    return;
  }
  int gid  = blockIdx.x * 256 + threadIdx.x;
  int lane = gid & 63;
  int frag = gid >> 6;
  int kk   = frag & 3;
  int w    = (frag >> 2) & 3;
  int term = (frag >> 4) & 1;
  int mat  = frag >> 5;
  const float* src = mat ? query_w : key_w;
  int n = w * 16 + (lane & 15);
  int g = lane >> 4;
  uint16_t o[8];
#pragma unroll
  for (int j = 0; j < 8; ++j) {
    int k = kk * 32 + g * 4 + (j & 3) + 16 * (j >> 2);
    float v = src[k * L_ + n];
    uint16_t hi = f2bf(v);
    if (term == 0) o[j] = hi;
    else           o[j] = f2bf(v - bfbits2f(hi));
  }
  uint16_t* dst = wfrag + (size_t)frag * 512 + lane * 8;
#pragma unroll
  for (int j = 0; j < 8; ++j) dst[j] = o[j];
}

// ---------------------------------------------------------------------------
// attn_partial: r17 body EXACTLY (53.9us verified) — no setprio (r18 proved
// it regresses 21% here: barrier-locked waves + DS reads inside the elevated
// region = priority inversion, m190 pattern). Only r18 carry-over: no
// empty-record writes (combine is vb-bounded).
// ---------------------------------------------------------------------------
__global__ __launch_bounds__(256, 3) void attn_partial(
    const float* __restrict__ seq, const int* __restrict__ lens,
    const uint16_t* __restrict__ wfrag,
    float2* __restrict__ msbuf, float* __restrict__ accbuf) {
  const int b    = blockIdx.y;
  const int xb   = blockIdx.x;
  const int tid  = threadIdx.x;
  const int lane = tid & 63;
  const int wv   = tid >> 6;
  const int len  = lens[b];

  const int nsc_valid = (len + SUB - 1) >> 6;
  int nvalid = (nsc_valid > xb) ? ((nsc_valid - xb + NXB - 1) >> 5) : 0;
  if (nvalid > 4) nvalid = 4;
  if (nvalid == 0) return;

  __shared__ uint16_t XFhi[SUB * XSF];
  __shared__ uint16_t XFlo[SUB * XSF];
  __shared__ float lpart[4][64];
  __shared__ f32x4 accredv[256];

  s16x8 wkh[4], wkl[4], wqh[4], wql[4];
#pragma unroll
  for (int kk = 0; kk < 4; ++kk) {
    wkh[kk] = *(const s16x8*)(wfrag + (size_t)( 0 + wv * 4 + kk) * 512 + lane * 8);
    wkl[kk] = *(const s16x8*)(wfrag + (size_t)(16 + wv * 4 + kk) * 512 + lane * 8);
    wqh[kk] = *(const s16x8*)(wfrag + (size_t)(32 + wv * 4 + kk) * 512 + lane * 8);
    wql[kk] = *(const s16x8*)(wfrag + (size_t)(48 + wv * 4 + kk) * 512 + lane * 8);
  }
  // (no pin — r12/r17 config; compiler free to sink under the soft 170 cap)

  const int tokb = tid >> 5;
  const int p0 = ((tid >> 3) & 3) * 32 + (tid & 3) * 8 + ((tid >> 2) & 1) * 4;
  const int c  = lane & 15;
  const int g2 = lane >> 4;

  const float* spb = seq + (size_t)b * T_ * D_;

  f32x4 v[8];
  {
    const float* sp = spb + (size_t)xb * SUB * D_;
#pragma unroll
    for (int i = 0; i < 8; ++i) v[i] = ((const f32x4*)sp)[tid + i * 256];
  }

  for (int vi = 0; vi < nvalid; ++vi) {
    const int s = xb + NXB * vi;
    const int tstart = s * SUB;

    // ---- conv: RNE hi + compensated lo into frag-contiguous LDS (r12) ----
#pragma unroll
    for (int i = 0; i < 8; ++i) {
      int tok = tokb + i * 8;
      f32x4 x = v[i];
      uint16_t h0 = f2bf(x[0]), h1 = f2bf(x[1]), h2 = f2bf(x[2]), h3 = f2bf(x[3]);
      *(s16x4*)(&XFhi[tok * XSF + p0]) = (s16x4){(short)h0, (short)h1, (short)h2, (short)h3};
      uint16_t l0 = f2bf(x[0] - bfbits2f(h0));
      uint16_t l1 = f2bf(x[1] - bfbits2f(h1));
      uint16_t l2 = f2bf(x[2] - bfbits2f(h2));
      uint16_t l3 = f2bf(x[3] - bfbits2f(h3));
      *(s16x4*)(&XFlo[tok * XSF + p0]) = (s16x4){(short)l0, (short)l1, (short)l2, (short)l3};
    }
    __syncthreads();                               // bar1: XF ready

    // ---- K = X Wk, Q = X Wq (XhWh + XhWl + XlWh) ----
    f32x4 kacc[4], qacc[4];
#pragma unroll
    for (int m = 0; m < 4; ++m) {
      kacc[m] = (f32x4){0.f, 0.f, 0.f, 0.f};
      qacc[m] = (f32x4){0.f, 0.f, 0.f, 0.f};
    }
#pragma unroll
    for (int kk = 0; kk < 4; ++kk) {
#pragma unroll
      for (int m = 0; m < 4; ++m) {
        const int eo = (m * 16 + c) * XSF + kk * 32 + g2 * 8;
        s16x8 ah = *(const s16x8*)(&XFhi[eo]);
        s16x8 al = *(const s16x8*)(&XFlo[eo]);
        kacc[m] = __builtin_amdgcn_mfma_f32_16x16x32_bf16(ah, wkh[kk], kacc[m], 0, 0, 0);
        kacc[m] = __builtin_amdgcn_mfma_f32_16x16x32_bf16(ah, wkl[kk], kacc[m], 0, 0, 0);
        kacc[m] = __builtin_amdgcn_mfma_f32_16x16x32_bf16(al, wkh[kk], kacc[m], 0, 0, 0);
        qacc[m] = __builtin_amdgcn_mfma_f32_16x16x32_bf16(ah, wqh[kk], qacc[m], 0, 0, 0);
        qacc[m] = __builtin_amdgcn_mfma_f32_16x16x32_bf16(ah, wql[kk], qacc[m], 0, 0, 0);
        qacc[m] = __builtin_amdgcn_mfma_f32_16x16x32_bf16(al, wqh[kk], qacc[m], 0, 0, 0);
      }
    }

    // ---- logits: k*q, DPP row_ror reduce over the 16-lane L-slice ----
#pragma unroll
    for (int m = 0; m < 4; ++m) {
#pragma unroll
      for (int r = 0; r < 4; ++r) {
        float val = kacc[m][r] * qacc[m][r];
        val = dpp_add<0x121>(val);
        val = dpp_add<0x122>(val);
        val = dpp_add<0x124>(val);
        val = dpp_add<0x128>(val);
        if (c == 0) lpart[wv][m * 16 + g2 * 4 + r] = val;
      }
    }
    __syncthreads();                               // bar2: lpart ready

    // ---- single-pass softmax (all waves redundant; DPP + 2 shfl) ----
    float logit = lpart[0][lane] + lpart[1][lane] + lpart[2][lane] + lpart[3][lane];
    logit = (tstart + lane < len) ? logit : -1e30f;
    float mx = logit;
    mx = dpp_max<0x121>(mx); mx = dpp_max<0x122>(mx);
    mx = dpp_max<0x124>(mx); mx = dpp_max<0x128>(mx);
    mx = fmaxf(mx, __shfl_xor(mx, 16));
    mx = fmaxf(mx, __shfl_xor(mx, 32));
    float wt = __expf(logit - mx);
    float ss = wt;
    ss = dpp_add<0x121>(ss); ss = dpp_add<0x122>(ss);
    ss = dpp_add<0x124>(ss); ss = dpp_add<0x128>(ss);
    ss += __shfl_xor(ss, 16);
    ss += __shfl_xor(ss, 32);

    // ---- pool from fp32 REGISTERS (exact); weights via v_readlane ----
    f32x4 pacc = (f32x4){0.f, 0.f, 0.f, 0.f};
#pragma unroll
    for (int i = 0; i < 8; ++i) {
      float wa = rdlane(wt, 2 * wv + 8 * i);       // lanes 0-31 token
      float wb = rdlane(wt, 2 * wv + 1 + 8 * i);   // lanes 32-63 token
      float w = (lane >= 32) ? wb : wa;
#pragma unroll
      for (int e = 0; e < 4; ++e) pacc[e] += w * v[i][e];
    }

    // ---- cross-thread pool reduce + SoA record write (r12 semantics) ----
    accredv[tid] = pacc;
    __syncthreads();                               // bar3: accredv ready
    if (tid < 32) {
      f32x4 r2 = accredv[tid];
#pragma unroll
      for (int k = 1; k < 8; ++k) r2 += accredv[tid + 32 * k];
      *(f32x4*)(accbuf + ((size_t)(b * NSC + s)) * D_ + tid * 4) = r2;
    }
    if (tid == 0) msbuf[b * NSC + s] = make_float2(mx, ss);

    // ---- LATE prefetch (r17-verified position) ----
    if (vi + 1 < nvalid) {
      const float* sp = spb + (size_t)(s + NXB) * SUB * D_;
#pragma unroll
      for (int i = 0; i < 8; ++i) v[i] = ((const f32x4*)sp)[tid + i * 256];
    }
  }
}

// ---------------------------------------------------------------------------
// combine: merge the vb valid subchunk-partials per batch, add bias
// (r9-verified: reads only i < vb; invalid slots never touched).
// ---------------------------------------------------------------------------
__global__ __launch_bounds__(256) void attn_combine(
    const float2* __restrict__ msbuf, const float* __restrict__ accbuf,
    const int* __restrict__ lens,
    const float* __restrict__ bias, float* __restrict__ out) {
  const int b = blockIdx.x;
  const int tid = threadIdx.x;
  const int vb = (lens[b] + SUB - 1) >> 6;       // valid records, >= 1
  __shared__ float red[4];
  __shared__ float wexp[NSC];
  __shared__ float halfsum[D_];

  float2 v = (tid < vb) ? msbuf[b * NSC + tid] : make_float2(-1e30f, 0.f);
  float m = v.x;
  m = fmaxf(m, __shfl_xor(m, 32)); m = fmaxf(m, __shfl_xor(m, 16));
  m = fmaxf(m, __shfl_xor(m, 8));  m = fmaxf(m, __shfl_xor(m, 4));
  m = fmaxf(m, __shfl_xor(m, 2));  m = fmaxf(m, __shfl_xor(m, 1));
  if ((tid & 63) == 0) red[tid >> 6] = m;
  __syncthreads();
  const float M = fmaxf(fmaxf(red[0], red[1]), fmaxf(red[2], red[3]));
  float e = (tid < vb) ? __expf(v.x - M) : 0.f;
  if (tid < NSC) wexp[tid] = e;
  float se = e * v.y;
  se += __shfl_xor(se, 32); se += __shfl_xor(se, 16); se += __shfl_xor(se, 8);
  se += __shfl_xor(se, 4);  se += __shfl_xor(se, 2);  se += __shfl_xor(se, 1);
  __syncthreads();
  if ((tid & 63) == 0) red[tid >> 6] = se;
  __syncthreads();
  const float S = red[0] + red[1] + red[2] + red[3];

  const int d = tid & 127;
  const int h = tid >> 7;
  const int i0 = h * 64;
  const int i1 = min(vb, i0 + 64);
  const float* ap = accbuf + ((size_t)b * NSC + i0) * D_ + d;
  float sum = 0.f;
  for (int i = i0; i < i1; ++i) sum += wexp[i] * ap[(size_t)(i - i0) * D_];
  if (h == 1) halfsum[d] = sum;
  __syncthreads();
  if (h == 0) {
    float rr = sum + ((vb > 64) ? halfsum[d] : 0.f);
    out[b * D_ + d] = ((S > 0.f) ? (rr / S) : 0.f) + bias[d];
  }
}

extern "C" void kernel_launch(void* const* d_in, const int* in_sizes, int n_in,
                              void* d_out, int out_size, void* d_ws, size_t ws_size,
                              hipStream_t stream) {
  const float* seq     = (const float*)d_in[0];
  const void*  len_raw = d_in[1];
  const float* key_w   = (const float*)d_in[2];
  const float* query_w = (const float*)d_in[3];
  const float* bias    = (const float*)d_in[4];
  float*       out     = (float*)d_out;

  uint16_t* wfrag  = (uint16_t*)d_ws;                          // 64 KB
  float2*   msbuf  = (float2*)((char*)d_ws + 65536);           // 64 KB
  float*    accbuf = (float*)((char*)d_ws + 131072);           // 4 MB
  int*      lens   = (int*)((char*)d_ws + 131072 + 4194304);   // 256 B

  prep<<<dim3(17), dim3(256), 0, stream>>>(key_w, query_w, len_raw, wfrag, lens);
  attn_partial<<<dim3(NXB, B_), dim3(256), 0, stream>>>(seq, lens, wfrag, msbuf, accbuf);
  attn_combine<<<dim3(B_), dim3(256), 0, stream>>>(msbuf, accbuf, lens, bias, out);
}

// Round 20
// 53.823 us; speedup vs baseline: 1.2203x; 1.2203x over previous
//
#include <hip/hip_runtime.h>
#include <hip/hip_bf16.h>
#include <stdint.h>

#define B_   64
#define T_   8192
#define D_   128
#define L_   64
#define SUB  64        // tokens per subchunk
#define NSC  128       // subchunks per batch (T/SUB)
#define NXB  32        // blocks per batch; each owns NSC/NXB = 4 subchunk slots
#define XSF  136       // padded LDS row stride (bf16 elems), HW-verified layout

typedef float f32x4 __attribute__((ext_vector_type(4)));
typedef short s16x8 __attribute__((ext_vector_type(8)));
typedef short s16x4 __attribute__((ext_vector_type(4)));

__device__ __forceinline__ uint16_t f2bf(float f) {
  __hip_bfloat16 h = __float2bfloat16(f);          // HW RNE
  return *(uint16_t*)&h;
}
__device__ __forceinline__ float bfbits2f(uint16_t h) {
  union { uint32_t u; float f; } c; c.u = ((uint32_t)h) << 16; return c.f;
}

// DPP row_ror reduces (r10-verified: -21%): VALU-pipe cross-lane, 16-lane rows.
template <int CTRL>
__device__ __forceinline__ float dpp_add(float v) {
  int t = __builtin_amdgcn_update_dpp(0, __builtin_bit_cast(int, v), CTRL, 0xf, 0xf, false);
  return v + __builtin_bit_cast(float, t);
}
template <int CTRL>
__device__ __forceinline__ float dpp_max(float v) {
  int t = __builtin_amdgcn_update_dpp(0, __builtin_bit_cast(int, v), CTRL, 0xf, 0xf, false);
  return fmaxf(v, __builtin_bit_cast(float, t));
}
__device__ __forceinline__ float rdlane(float v, int lane) {
  return __builtin_bit_cast(float, __builtin_amdgcn_readlane(__builtin_bit_cast(int, v), lane));
}

// ---------------------------------------------------------------------------
// prep: blocks 0..15 pack W_k/W_q into bf16 hi/lo MFMA B-fragment order;
// block 16 normalizes lengths (robust to int32 OR int64 input).
// B-frag: n = w*16 + (lane&15); k = kk*32 + 4*(lane>>4) + (j&3) + 16*(j>>2)
// frag id = mat*32 + term*16 + w*4 + kk.   (HW-verified r2-r19)
// ---------------------------------------------------------------------------
__global__ void prep(const float* __restrict__ key_w,
                     const float* __restrict__ query_w,
                     const void* __restrict__ lengths_raw,
                     uint16_t* __restrict__ wfrag,
                     int* __restrict__ lens) {
  if (blockIdx.x == 16) {
    const int tid = threadIdx.x;
    if (tid >= 64) return;
    const int* s32 = (const int*)lengths_raw;
    bool odd_zero = (tid < 32) ? (s32[2 * tid + 1] == 0) : true;
    bool is64 = __all(odd_zero);
    int v;
    if (is64) v = (int)((const long long*)lengths_raw)[tid];
    else      v = s32[tid];
    lens[tid] = v;
    return;
  }
  int gid  = blockIdx.x * 256 + threadIdx.x;
  int lane = gid & 63;
  int frag = gid >> 6;
  int kk   = frag & 3;
  int w    = (frag >> 2) & 3;
  int term = (frag >> 4) & 1;
  int mat  = frag >> 5;
  const float* src = mat ? query_w : key_w;
  int n = w * 16 + (lane & 15);
  int g = lane >> 4;
  uint16_t o[8];
#pragma unroll
  for (int j = 0; j < 8; ++j) {
    int k = kk * 32 + g * 4 + (j & 3) + 16 * (j >> 2);
    float v = src[k * L_ + n];
    uint16_t hi = f2bf(v);
    if (term == 0) o[j] = hi;
    else           o[j] = f2bf(v - bfbits2f(hi));
  }
  uint16_t* dst = wfrag + (size_t)frag * 512 + lane * 8;
#pragma unroll
  for (int j = 0; j < 8; ++j) dst[j] = o[j];
}

// ---------------------------------------------------------------------------
// attn_partial: r17 EXACT (53.9us verified). Empty-record writes restored —
// r18/r19 proved the vb-bounded combine (dynamic loop bounds, no unroll, no
// ILP on a 64-block latency-bound kernel) costs ~12us; fixed-128-record
// combine with unroll-8 needs all records initialized.
// ---------------------------------------------------------------------------
__global__ __launch_bounds__(256, 3) void attn_partial(
    const float* __restrict__ seq, const int* __restrict__ lens,
    const uint16_t* __restrict__ wfrag,
    float2* __restrict__ msbuf, float* __restrict__ accbuf) {
  const int b    = blockIdx.y;
  const int xb   = blockIdx.x;
  const int tid  = threadIdx.x;
  const int lane = tid & 63;
  const int wv   = tid >> 6;
  const int len  = lens[b];

  const int nsc_valid = (len + SUB - 1) >> 6;
  int nvalid = (nsc_valid > xb) ? ((nsc_valid - xb + NXB - 1) >> 5) : 0;
  if (nvalid > 4) nvalid = 4;

  for (int i = nvalid; i < 4; ++i) {
    const int s = xb + NXB * i;
    if (tid == 0) msbuf[b * NSC + s] = make_float2(-1e30f, 0.f);
    if (tid < 32)
      *(f32x4*)(accbuf + ((size_t)(b * NSC + s)) * D_ + tid * 4) =
          (f32x4){0.f, 0.f, 0.f, 0.f};
  }
  if (nvalid == 0) return;

  __shared__ uint16_t XFhi[SUB * XSF];
  __shared__ uint16_t XFlo[SUB * XSF];
  __shared__ float lpart[4][64];
  __shared__ f32x4 accredv[256];

  s16x8 wkh[4], wkl[4], wqh[4], wql[4];
#pragma unroll
  for (int kk = 0; kk < 4; ++kk) {
    wkh[kk] = *(const s16x8*)(wfrag + (size_t)( 0 + wv * 4 + kk) * 512 + lane * 8);
    wkl[kk] = *(const s16x8*)(wfrag + (size_t)(16 + wv * 4 + kk) * 512 + lane * 8);
    wqh[kk] = *(const s16x8*)(wfrag + (size_t)(32 + wv * 4 + kk) * 512 + lane * 8);
    wql[kk] = *(const s16x8*)(wfrag + (size_t)(48 + wv * 4 + kk) * 512 + lane * 8);
  }
  // (no pin — r12/r17 config; compiler free to sink under the soft 170 cap)

  const int tokb = tid >> 5;
  const int p0 = ((tid >> 3) & 3) * 32 + (tid & 3) * 8 + ((tid >> 2) & 1) * 4;
  const int c  = lane & 15;
  const int g2 = lane >> 4;

  const float* spb = seq + (size_t)b * T_ * D_;

  f32x4 v[8];
  {
    const float* sp = spb + (size_t)xb * SUB * D_;
#pragma unroll
    for (int i = 0; i < 8; ++i) v[i] = ((const f32x4*)sp)[tid + i * 256];
  }

  for (int vi = 0; vi < nvalid; ++vi) {
    const int s = xb + NXB * vi;
    const int tstart = s * SUB;

    // ---- conv: RNE hi + compensated lo into frag-contiguous LDS (r12) ----
#pragma unroll
    for (int i = 0; i < 8; ++i) {
      int tok = tokb + i * 8;
      f32x4 x = v[i];
      uint16_t h0 = f2bf(x[0]), h1 = f2bf(x[1]), h2 = f2bf(x[2]), h3 = f2bf(x[3]);
      *(s16x4*)(&XFhi[tok * XSF + p0]) = (s16x4){(short)h0, (short)h1, (short)h2, (short)h3};
      uint16_t l0 = f2bf(x[0] - bfbits2f(h0));
      uint16_t l1 = f2bf(x[1] - bfbits2f(h1));
      uint16_t l2 = f2bf(x[2] - bfbits2f(h2));
      uint16_t l3 = f2bf(x[3] - bfbits2f(h3));
      *(s16x4*)(&XFlo[tok * XSF + p0]) = (s16x4){(short)l0, (short)l1, (short)l2, (short)l3};
    }
    __syncthreads();                               // bar1: XF ready

    // ---- K = X Wk, Q = X Wq (XhWh + XhWl + XlWh) ----
    f32x4 kacc[4], qacc[4];
#pragma unroll
    for (int m = 0; m < 4; ++m) {
      kacc[m] = (f32x4){0.f, 0.f, 0.f, 0.f};
      qacc[m] = (f32x4){0.f, 0.f, 0.f, 0.f};
    }
#pragma unroll
    for (int kk = 0; kk < 4; ++kk) {
#pragma unroll
      for (int m = 0; m < 4; ++m) {
        const int eo = (m * 16 + c) * XSF + kk * 32 + g2 * 8;
        s16x8 ah = *(const s16x8*)(&XFhi[eo]);
        s16x8 al = *(const s16x8*)(&XFlo[eo]);
        kacc[m] = __builtin_amdgcn_mfma_f32_16x16x32_bf16(ah, wkh[kk], kacc[m], 0, 0, 0);
        kacc[m] = __builtin_amdgcn_mfma_f32_16x16x32_bf16(ah, wkl[kk], kacc[m], 0, 0, 0);
        kacc[m] = __builtin_amdgcn_mfma_f32_16x16x32_bf16(al, wkh[kk], kacc[m], 0, 0, 0);
        qacc[m] = __builtin_amdgcn_mfma_f32_16x16x32_bf16(ah, wqh[kk], qacc[m], 0, 0, 0);
        qacc[m] = __builtin_amdgcn_mfma_f32_16x16x32_bf16(ah, wql[kk], qacc[m], 0, 0, 0);
        qacc[m] = __builtin_amdgcn_mfma_f32_16x16x32_bf16(al, wqh[kk], qacc[m], 0, 0, 0);
      }
    }

    // ---- logits: k*q, DPP row_ror reduce over the 16-lane L-slice ----
#pragma unroll
    for (int m = 0; m < 4; ++m) {
#pragma unroll
      for (int r = 0; r < 4; ++r) {
        float val = kacc[m][r] * qacc[m][r];
        val = dpp_add<0x121>(val);
        val = dpp_add<0x122>(val);
        val = dpp_add<0x124>(val);
        val = dpp_add<0x128>(val);
        if (c == 0) lpart[wv][m * 16 + g2 * 4 + r] = val;
      }
    }
    __syncthreads();                               // bar2: lpart ready

    // ---- single-pass softmax (all waves redundant; DPP + 2 shfl) ----
    float logit = lpart[0][lane] + lpart[1][lane] + lpart[2][lane] + lpart[3][lane];
    logit = (tstart + lane < len) ? logit : -1e30f;
    float mx = logit;
    mx = dpp_max<0x121>(mx); mx = dpp_max<0x122>(mx);
    mx = dpp_max<0x124>(mx); mx = dpp_max<0x128>(mx);
    mx = fmaxf(mx, __shfl_xor(mx, 16));
    mx = fmaxf(mx, __shfl_xor(mx, 32));
    float wt = __expf(logit - mx);
    float ss = wt;
    ss = dpp_add<0x121>(ss); ss = dpp_add<0x122>(ss);
    ss = dpp_add<0x124>(ss); ss = dpp_add<0x128>(ss);
    ss += __shfl_xor(ss, 16);
    ss += __shfl_xor(ss, 32);

    // ---- pool from fp32 REGISTERS (exact); weights via v_readlane ----
    f32x4 pacc = (f32x4){0.f, 0.f, 0.f, 0.f};
#pragma unroll
    for (int i = 0; i < 8; ++i) {
      float wa = rdlane(wt, 2 * wv + 8 * i);       // lanes 0-31 token
      float wb = rdlane(wt, 2 * wv + 1 + 8 * i);   // lanes 32-63 token
      float w = (lane >= 32) ? wb : wa;
#pragma unroll
      for (int e = 0; e < 4; ++e) pacc[e] += w * v[i][e];
    }

    // ---- cross-thread pool reduce + SoA record write (r12 semantics) ----
    accredv[tid] = pacc;
    __syncthreads();                               // bar3: accredv ready
    if (tid < 32) {
      f32x4 r2 = accredv[tid];
#pragma unroll
      for (int k = 1; k < 8; ++k) r2 += accredv[tid + 32 * k];
      *(f32x4*)(accbuf + ((size_t)(b * NSC + s)) * D_ + tid * 4) = r2;
    }
    if (tid == 0) msbuf[b * NSC + s] = make_float2(mx, ss);

    // ---- LATE prefetch: v is dead now; next conv uses the new tile.
    if (vi + 1 < nvalid) {
      const float* sp = spb + (size_t)(s + NXB) * SUB * D_;
#pragma unroll
      for (int i = 0; i < 8; ++i) v[i] = ((const f32x4*)sp)[tid + i * 256];
    }
  }
}

// ---------------------------------------------------------------------------
// combine: parallel merge of the 128 subchunk-partials per batch, add bias.
// FIXED 128-record loop with unroll 8 (r17-verified) — dynamic vb bounds
// kill the unroll/ILP and cost ~12us on this latency-bound 64-block kernel.
// ---------------------------------------------------------------------------
__global__ __launch_bounds__(256) void attn_combine(
    const float2* __restrict__ msbuf, const float* __restrict__ accbuf,
    const float* __restrict__ bias, float* __restrict__ out) {
  const int b = blockIdx.x;
  const int tid = threadIdx.x;
  __shared__ float red[4];
  __shared__ float wexp[NSC];
  __shared__ float halfsum[D_];

  float2 v = (tid < NSC) ? msbuf[b * NSC + tid] : make_float2(-1e30f, 0.f);
  float m = v.x;
  m = fmaxf(m, __shfl_xor(m, 32)); m = fmaxf(m, __shfl_xor(m, 16));
  m = fmaxf(m, __shfl_xor(m, 8));  m = fmaxf(m, __shfl_xor(m, 4));
  m = fmaxf(m, __shfl_xor(m, 2));  m = fmaxf(m, __shfl_xor(m, 1));
  if ((tid & 63) == 0) red[tid >> 6] = m;
  __syncthreads();
  const float M = fmaxf(fmaxf(red[0], red[1]), fmaxf(red[2], red[3]));
  float e = (tid < NSC) ? __expf(v.x - M) : 0.f;
  if (tid < NSC) wexp[tid] = e;
  float se = e * v.y;
  se += __shfl_xor(se, 32); se += __shfl_xor(se, 16); se += __shfl_xor(se, 8);
  se += __shfl_xor(se, 4);  se += __shfl_xor(se, 2);  se += __shfl_xor(se, 1);
  __syncthreads();
  if ((tid & 63) == 0) red[tid >> 6] = se;
  __syncthreads();
  const float S = red[0] + red[1] + red[2] + red[3];

  const int d = tid & 127;
  const int h = tid >> 7;
  const float* ap = accbuf + ((size_t)b * NSC + h * 64) * D_ + d;
  float sum = 0.f;
#pragma unroll 8
  for (int i = 0; i < 64; ++i) sum += wexp[h * 64 + i] * ap[(size_t)i * D_];
  if (h == 1) halfsum[d] = sum;
  __syncthreads();
  if (h == 0) {
    float r = sum + halfsum[d];
    out[b * D_ + d] = ((S > 0.f) ? (r / S) : 0.f) + bias[d];
  }
}

extern "C" void kernel_launch(void* const* d_in, const int* in_sizes, int n_in,
                              void* d_out, int out_size, void* d_ws, size_t ws_size,
                              hipStream_t stream) {
  const float* seq     = (const float*)d_in[0];
  const void*  len_raw = d_in[1];
  const float* key_w   = (const float*)d_in[2];
  const float* query_w = (const float*)d_in[3];
  const float* bias    = (const float*)d_in[4];
  float*       out     = (float*)d_out;

  uint16_t* wfrag  = (uint16_t*)d_ws;                          // 64 KB
  float2*   msbuf  = (float2*)((char*)d_ws + 65536);           // 64 KB
  float*    accbuf = (float*)((char*)d_ws + 131072);           // 4 MB
  int*      lens   = (int*)((char*)d_ws + 131072 + 4194304);   // 256 B

  prep<<<dim3(17), dim3(256), 0, stream>>>(key_w, query_w, len_raw, wfrag, lens);
  attn_partial<<<dim3(NXB, B_), dim3(256), 0, stream>>>(seq, lens, wfrag, msbuf, accbuf);
  attn_combine<<<dim3(B_), dim3(256), 0, stream>>>(msbuf, accbuf, bias, out);
}